// Round 1
// baseline (317.710 us; speedup 1.0000x reference)
//
#include <hip/hip_runtime.h>
#include <hip/hip_bf16.h>
#include <stdint.h>

#define HID 512
#define NACT 64
#define NAG 8
#define NR 16384            // 2048 * 8 rows
#define BMT 128             // row tile for grouped GEMMs
#define MAXTILES 136        // NR/BMT + NAG

typedef __bf16 bf16_t;
typedef __bf16 bf16x4 __attribute__((ext_vector_type(4)));
typedef __bf16 bf16x8 __attribute__((ext_vector_type(8)));
typedef float  f32x16 __attribute__((ext_vector_type(16)));

#define MFMA32(a,b,c) __builtin_amdgcn_mfma_f32_32x32x16_bf16((a),(b),(c),0,0,0)

// ---------------- workspace layout (bytes) ----------------
#define OFF_META 0                      // 512 ints: [0:8) counts, [8:16) cursor, 16 ntiles,
                                        // [32:192) td_start, [192:352) td_rows, [352:512) td_agent
#define OFF_PERM 4096                   // 16384 ints
#define OFF_WM1  (128*1024)             // 8*512*512 bf16
#define OFF_WM2  (OFF_WM1 + NAG*HID*HID*2)
#define OFF_WM3  (OFF_WM2 + NAG*HID*HID*2)
#define OFF_WM4  (OFF_WM3 + NAG*HID*HID*2)
#define OFF_WIH  (OFF_WM4 + NAG*NACT*HID*2)
#define OFF_WHH  (OFF_WIH + 3*HID*HID*2)
#define OFF_BUFA (OFF_WHH + 3*HID*HID*2)   // X1 then Q2 (bf16 [NR][512], sorted order)
#define OFF_BUFB (OFF_BUFA + (size_t)NR*HID*2)  // H then Q3

// ---------------- helpers ----------------
__device__ inline void load_lds16(const void* g, void* l) {
  __builtin_amdgcn_global_load_lds((__attribute__((address_space(1))) void*)g,
                                   (__attribute__((address_space(3))) void*)l,
                                   16, 0, 0);
}

// LDS tile convention: [R rows][64 bf16 cols], 128B/row; 16B slot s of row r holds
// global col-block (s ^ (r&7)).  (swizzle => ds_read_b128 fragments are 2-way = free)
__device__ inline bf16x8 lds_frag(const bf16_t* base, int r, int cb) {
  return *(const bf16x8*)((const char*)base + r*128 + ((cb*16) ^ ((r&7)<<4)));
}

__device__ inline void store8bf(void* dst, float4 a, float4 b) {
  union { bf16_t h[8]; uint4 u; } p;
  p.h[0]=(bf16_t)a.x; p.h[1]=(bf16_t)a.y; p.h[2]=(bf16_t)a.z; p.h[3]=(bf16_t)a.w;
  p.h[4]=(bf16_t)b.x; p.h[5]=(bf16_t)b.y; p.h[6]=(bf16_t)b.z; p.h[7]=(bf16_t)b.w;
  *(uint4*)dst = p.u;
}

__device__ inline float kmask(float w, float t) {  // sign(w)*relu(|w|-sigmoid(t))
  float s = 1.f / (1.f + __expf(-t));
  float m = fabsf(w) - s;
  return m > 0.f ? copysignf(m, w) : 0.f;
}

__device__ inline float sigm(float x) { return 1.f / (1.f + __expf(-x)); }
__device__ inline float tanh_f(float x) {
  float e = __expf(2.f * fabsf(x));
  return copysignf(1.f - 2.f/(e + 1.f), x);
}

// ---------------- weight prep: mask + bf16 convert ----------------
// vector index v covers (4 elems each): wm1,wm2,wm3 (524288 each), wm4 (65536), wih, whh (196608 each)
__global__ void k_prep(const float* __restrict__ f1w, const float* __restrict__ f1t,
                       const float* __restrict__ f2w, const float* __restrict__ f2t,
                       const float* __restrict__ f3w, const float* __restrict__ f3t,
                       const float* __restrict__ f4w, const float* __restrict__ f4t,
                       const float* __restrict__ gih, const float* __restrict__ ghh,
                       bf16_t* __restrict__ wm1, bf16_t* __restrict__ wm2,
                       bf16_t* __restrict__ wm3, bf16_t* __restrict__ wm4,
                       bf16_t* __restrict__ wihb, bf16_t* __restrict__ whhb,
                       int* __restrict__ meta)
{
  const int tid = threadIdx.x;
  if (blockIdx.x == 0 && tid < 32) meta[tid] = 0;   // zero counts+cursors
  long v = (long)blockIdx.x * 256 + tid;
  const long VR1 = 524288;
  if (v < 3*VR1) {
    int which = (int)(v / VR1);
    long e = (v - (long)which*VR1) * 4;
    const float* W = which==0 ? f1w : (which==1 ? f2w : f3w);
    const float* T = which==0 ? f1t : (which==1 ? f2t : f3t);
    bf16_t* O = which==0 ? wm1 : (which==1 ? wm2 : wm3);
    long oi = e & (long)(HID*HID - 1);
    float4 w = *(const float4*)(W + oi);
    float4 t = *(const float4*)(T + e);
    bf16x4 o;
    o[0]=(bf16_t)kmask(w.x,t.x); o[1]=(bf16_t)kmask(w.y,t.y);
    o[2]=(bf16_t)kmask(w.z,t.z); o[3]=(bf16_t)kmask(w.w,t.w);
    *(bf16x4*)(O + e) = o;
  } else if (v < 3*VR1 + 65536) {
    long e = (v - 3*VR1) * 4;
    long oi = e & (long)(NACT*HID - 1);
    float4 w = *(const float4*)(f4w + oi);
    float4 t = *(const float4*)(f4t + e);
    bf16x4 o;
    o[0]=(bf16_t)kmask(w.x,t.x); o[1]=(bf16_t)kmask(w.y,t.y);
    o[2]=(bf16_t)kmask(w.z,t.z); o[3]=(bf16_t)kmask(w.w,t.w);
    *(bf16x4*)(wm4 + e) = o;
  } else if (v < 3*VR1 + 65536 + 196608) {
    long e = (v - (3*VR1 + 65536)) * 4;
    float4 x = *(const float4*)(gih + e);
    bf16x4 o; o[0]=(bf16_t)x.x; o[1]=(bf16_t)x.y; o[2]=(bf16_t)x.z; o[3]=(bf16_t)x.w;
    *(bf16x4*)(wihb + e) = o;
  } else if (v < 3*VR1 + 65536 + 2*196608) {
    long e = (v - (3*VR1 + 65536 + 196608)) * 4;
    float4 x = *(const float4*)(ghh + e);
    bf16x4 o; o[0]=(bf16_t)x.x; o[1]=(bf16_t)x.y; o[2]=(bf16_t)x.z; o[3]=(bf16_t)x.w;
    *(bf16x4*)(whhb + e) = o;
  }
}

// ---------------- bucket rows by agent ----------------
__global__ void k_count(const int* __restrict__ ids, int* __restrict__ meta) {
  int n = blockIdx.x*256 + threadIdx.x;
  atomicAdd(&meta[ids[n]], 1);
}

__global__ void k_td(int* __restrict__ meta) {
  if (threadIdx.x != 0 || blockIdx.x != 0) return;
  int off = 0, nt = 0;
  for (int a = 0; a < NAG; ++a) {
    int c = meta[a];
    meta[8+a] = off;                 // cursor = group start
    for (int t = 0; t*BMT < c; ++t) {
      meta[32 + nt]  = off + t*BMT;            // tile start
      meta[192 + nt] = (c - t*BMT < BMT) ? (c - t*BMT) : BMT;  // rows
      meta[352 + nt] = a;                      // agent
      ++nt;
    }
    off += c;
  }
  meta[16] = nt;
}

__global__ void k_scatter(const int* __restrict__ ids, int* __restrict__ meta,
                          int* __restrict__ perm) {
  int n = blockIdx.x*256 + threadIdx.x;
  int a = ids[n];
  int pos = atomicAdd(&meta[8+a], 1);
  perm[pos] = n;
}

// ---------------- grouped kalei GEMM ----------------
// BM=128, BK=64, 4 waves (2x2), wave tile 64 x (BN/2), 32x32x16 MFMA.
// GATHER: A rows = inputs[perm[m]] fp32 -> bf16 (reg staged). else: A = bf16 sorted buf (glds).
// OUTMODE 0: relu(acc+b) -> bf16 buf (stride OTOT). 1: (acc+b) -> fp32 d_out scatter via perm.
template<int BN, int OTOT, bool GATHER, int OUTMODE>
__global__ __launch_bounds__(256)
void k_fc(const float* __restrict__ a_f32, const bf16_t* __restrict__ a_bf,
          const bf16_t* __restrict__ wbase, const float* __restrict__ bias,
          bf16_t* __restrict__ out_bf, float* __restrict__ out_f32,
          const int* __restrict__ meta, const int* __restrict__ perm)
{
  constexpr int FN = BN/64;
  const int bx = blockIdx.x;
  if (bx >= meta[16]) return;
  const int m0    = meta[32 + bx];
  const int rows  = meta[192 + bx];
  const int agent = meta[352 + bx];
  const int o0 = blockIdx.y * BN;
  const bf16_t* W = wbase + (size_t)agent * OTOT * HID;

  __shared__ bf16_t lA[BMT*64];
  __shared__ bf16_t lB[BN*64];

  const int tid = threadIdx.x, lane = tid & 63, wid = tid >> 6;
  const int wrow = wid & 1, wcol = wid >> 1;

  f32x16 zero;
  #pragma unroll
  for (int i = 0; i < 16; ++i) zero[i] = 0.f;
  f32x16 acc[2][FN];
  #pragma unroll
  for (int i = 0; i < 2; ++i)
    #pragma unroll
    for (int j = 0; j < FN; ++j) acc[i][j] = zero;

  for (int kp = 0; kp < HID/64; ++kp) {
    const int k0 = kp * 64;
    __syncthreads();
    if constexpr (GATHER) {
      #pragma unroll
      for (int it = 0; it < 4; ++it) {
        int t = it*256 + tid;
        int r = t >> 3, cb = t & 7;
        int rl = r < rows-1 ? r : rows-1;
        const float* sp = a_f32 + (size_t)perm[m0+rl]*HID + k0 + cb*8;
        float4 v0 = ((const float4*)sp)[0];
        float4 v1 = ((const float4*)sp)[1];
        store8bf((char*)lA + r*128 + ((cb*16) ^ ((r&7)<<4)), v0, v1);
      }
    } else {
      #pragma unroll
      for (int q = 0; q < 4; ++q) {
        int i = wid*4 + q;
        int r = i*8 + (lane>>3);
        int rl = r < rows-1 ? r : rows-1;
        int g = (lane&7) ^ ((lane>>3)&7);   // pre-swizzled global source block
        load_lds16(a_bf + (size_t)(m0+rl)*HID + k0 + g*8, (char*)lA + i*1024);
      }
    }
    #pragma unroll
    for (int q = 0; q < BN/32; ++q) {
      int i = wid*(BN/32) + q;
      int r = i*8 + (lane>>3);
      int g = (lane&7) ^ ((lane>>3)&7);
      load_lds16(W + (size_t)(o0+r)*HID + k0 + g*8, (char*)lB + i*1024);
    }
    __syncthreads();
    #pragma unroll
    for (int kk = 0; kk < 4; ++kk) {
      const int cbb = kk*2 + (lane>>5);
      bf16x8 af[2];
      #pragma unroll
      for (int fm = 0; fm < 2; ++fm) {
        int r = wrow*64 + fm*32 + (lane&31);
        af[fm] = lds_frag(lA, r, cbb);
      }
      #pragma unroll
      for (int fn = 0; fn < FN; ++fn) {
        int r = wcol*(BN/2) + fn*32 + (lane&31);
        bf16x8 bfv = lds_frag(lB, r, cbb);
        #pragma unroll
        for (int fm = 0; fm < 2; ++fm)
          acc[fm][fn] = MFMA32(af[fm], bfv, acc[fm][fn]);
      }
    }
  }

  // epilogue: C layout (32x32): col=lane&31, row=4*(lane>>5)+(g&3)+8*(g>>2)
  #pragma unroll
  for (int fn = 0; fn < FN; ++fn) {
    int col = o0 + wcol*(BN/2) + fn*32 + (lane&31);
    float bv = bias[col];
    #pragma unroll
    for (int fm = 0; fm < 2; ++fm) {
      #pragma unroll
      for (int g = 0; g < 16; ++g) {
        int rl = wrow*64 + fm*32 + 4*(lane>>5) + (g&3) + 8*(g>>2);
        if (rl < rows) {
          float y = acc[fm][fn][g] + bv;
          if constexpr (OUTMODE == 0) {
            y = fmaxf(y, 0.f);
            out_bf[(size_t)(m0+rl)*OTOT + col] = (bf16_t)y;
          } else {
            out_f32[(size_t)perm[m0+rl]*OTOT + col] = y;
          }
        }
      }
    }
  }
}

// ---------------- fused GRU ----------------
// 4 accumulators: ar (r-gate, K=1024), az (z-gate, K=1024), an (i_n, K=512 x-side),
// ah (h_n, K=512 h-side). 8 waves (2x4), wave tile 64x32 per acc. BM=128, BN=128.
__global__ __launch_bounds__(512)
void k_gru(const bf16_t* __restrict__ x1, const float* __restrict__ hidden,
           const bf16_t* __restrict__ wih, const bf16_t* __restrict__ whh,
           const float* __restrict__ bih, const float* __restrict__ bhh,
           bf16_t* __restrict__ hbuf, float* __restrict__ hout,
           const int* __restrict__ perm)
{
  const int m0 = blockIdx.x * BMT;
  const int j0 = blockIdx.y * 128;
  const int tid = threadIdx.x, lane = tid & 63, wid = tid >> 6;
  const int wrow = wid & 1, wcol = wid >> 1;

  __shared__ bf16_t lA[128*64];
  __shared__ bf16_t lB0[128*64];
  __shared__ bf16_t lB1[128*64];
  __shared__ bf16_t lB2[128*64];

  f32x16 zero;
  #pragma unroll
  for (int i = 0; i < 16; ++i) zero[i] = 0.f;
  f32x16 ar[2], az[2], an[2], ah[2];
  ar[0]=ar[1]=az[0]=az[1]=an[0]=an[1]=ah[0]=ah[1]=zero;

  // ---- phase X: A = x1 (sorted bf16), B = wih; accumulate ar, az, an ----
  for (int kp = 0; kp < 8; ++kp) {
    const int k0 = kp * 64;
    __syncthreads();
    #pragma unroll
    for (int q = 0; q < 2; ++q) {
      int i = wid*2 + q;
      int r = i*8 + (lane>>3);
      int g = (lane&7) ^ ((lane>>3)&7);
      load_lds16(x1  + (size_t)(m0+r)*HID        + k0 + g*8, (char*)lA  + i*1024);
      load_lds16(wih + (size_t)(j0+r)*HID        + k0 + g*8, (char*)lB0 + i*1024);
      load_lds16(wih + (size_t)(512+j0+r)*HID    + k0 + g*8, (char*)lB1 + i*1024);
      load_lds16(wih + (size_t)(1024+j0+r)*HID   + k0 + g*8, (char*)lB2 + i*1024);
    }
    __syncthreads();
    #pragma unroll
    for (int kk = 0; kk < 4; ++kk) {
      const int cbb = kk*2 + (lane>>5);
      bf16x8 af[2];
      #pragma unroll
      for (int fm = 0; fm < 2; ++fm)
        af[fm] = lds_frag(lA, wrow*64 + fm*32 + (lane&31), cbb);
      int rb = wcol*32 + (lane&31);
      bf16x8 b0 = lds_frag(lB0, rb, cbb);
      bf16x8 b1 = lds_frag(lB1, rb, cbb);
      bf16x8 b2 = lds_frag(lB2, rb, cbb);
      #pragma unroll
      for (int fm = 0; fm < 2; ++fm) {
        ar[fm] = MFMA32(af[fm], b0, ar[fm]);
        az[fm] = MFMA32(af[fm], b1, az[fm]);
        an[fm] = MFMA32(af[fm], b2, an[fm]);
      }
    }
  }
  // ---- phase H: A = hidden[perm[m]] fp32->bf16, B = whh; accumulate ar, az, ah ----
  for (int kp = 0; kp < 8; ++kp) {
    const int k0 = kp * 64;
    __syncthreads();
    #pragma unroll
    for (int it = 0; it < 2; ++it) {
      int t = it*512 + tid;
      int r = t >> 3, cb = t & 7;
      const float* sp = hidden + (size_t)perm[m0+r]*HID + k0 + cb*8;
      float4 v0 = ((const float4*)sp)[0];
      float4 v1 = ((const float4*)sp)[1];
      store8bf((char*)lA + r*128 + ((cb*16) ^ ((r&7)<<4)), v0, v1);
    }
    #pragma unroll
    for (int q = 0; q < 2; ++q) {
      int i = wid*2 + q;
      int r = i*8 + (lane>>3);
      int g = (lane&7) ^ ((lane>>3)&7);
      load_lds16(whh + (size_t)(j0+r)*HID      + k0 + g*8, (char*)lB0 + i*1024);
      load_lds16(whh + (size_t)(512+j0+r)*HID  + k0 + g*8, (char*)lB1 + i*1024);
      load_lds16(whh + (size_t)(1024+j0+r)*HID + k0 + g*8, (char*)lB2 + i*1024);
    }
    __syncthreads();
    #pragma unroll
    for (int kk = 0; kk < 4; ++kk) {
      const int cbb = kk*2 + (lane>>5);
      bf16x8 af[2];
      #pragma unroll
      for (int fm = 0; fm < 2; ++fm)
        af[fm] = lds_frag(lA, wrow*64 + fm*32 + (lane&31), cbb);
      int rb = wcol*32 + (lane&31);
      bf16x8 b0 = lds_frag(lB0, rb, cbb);
      bf16x8 b1 = lds_frag(lB1, rb, cbb);
      bf16x8 b2 = lds_frag(lB2, rb, cbb);
      #pragma unroll
      for (int fm = 0; fm < 2; ++fm) {
        ar[fm] = MFMA32(af[fm], b0, ar[fm]);
        az[fm] = MFMA32(af[fm], b1, az[fm]);
        ah[fm] = MFMA32(af[fm], b2, ah[fm]);
      }
    }
  }

  // ---- epilogue: gates + blend (h_prev in exact fp32) ----
  const int col = j0 + wcol*32 + (lane&31);
  const float b_r  = bih[col]        + bhh[col];
  const float b_z  = bih[512 + col]  + bhh[512 + col];
  const float b_in = bih[1024 + col];
  const float b_hn = bhh[1024 + col];
  #pragma unroll
  for (int fm = 0; fm < 2; ++fm) {
    #pragma unroll
    for (int g = 0; g < 16; ++g) {
      int rl = wrow*64 + fm*32 + 4*(lane>>5) + (g&3) + 8*(g>>2);
      int m = m0 + rl;
      int src = perm[m];
      float hp = hidden[(size_t)src*HID + col];
      float rg = sigm(ar[fm][g] + b_r);
      float zg = sigm(az[fm][g] + b_z);
      float ng = tanh_f(an[fm][g] + b_in + rg*(ah[fm][g] + b_hn));
      float h  = (1.f - zg)*ng + zg*hp;
      hbuf[(size_t)m*HID + col] = (bf16_t)h;
      hout[(size_t)src*HID + col] = h;
    }
  }
}

// ---------------- launch ----------------
extern "C" void kernel_launch(void* const* d_in, const int* in_sizes, int n_in,
                              void* d_out, int out_size, void* d_ws, size_t ws_size,
                              hipStream_t stream) {
  const float* inputs  = (const float*)d_in[0];
  const float* hidden  = (const float*)d_in[1];
  const int*   ids     = (const int*)  d_in[2];
  const float* fc1_w   = (const float*)d_in[3];
  const float* fc1_b   = (const float*)d_in[4];
  const float* fc1_t   = (const float*)d_in[5];
  const float* gru_wih = (const float*)d_in[6];
  const float* gru_whh = (const float*)d_in[7];
  const float* gru_bih = (const float*)d_in[8];
  const float* gru_bhh = (const float*)d_in[9];
  const float* fc2_w   = (const float*)d_in[10];
  const float* fc2_b   = (const float*)d_in[11];
  const float* fc2_t   = (const float*)d_in[12];
  const float* fc3_w   = (const float*)d_in[13];
  const float* fc3_b   = (const float*)d_in[14];
  const float* fc3_t   = (const float*)d_in[15];
  const float* fc4_w   = (const float*)d_in[16];
  const float* fc4_b   = (const float*)d_in[17];
  const float* fc4_t   = (const float*)d_in[18];

  char* ws = (char*)d_ws;
  int*    meta = (int*)   (ws + OFF_META);
  int*    perm = (int*)   (ws + OFF_PERM);
  bf16_t* wm1  = (bf16_t*)(ws + OFF_WM1);
  bf16_t* wm2  = (bf16_t*)(ws + OFF_WM2);
  bf16_t* wm3  = (bf16_t*)(ws + OFF_WM3);
  bf16_t* wm4  = (bf16_t*)(ws + OFF_WM4);
  bf16_t* wihb = (bf16_t*)(ws + OFF_WIH);
  bf16_t* whhb = (bf16_t*)(ws + OFF_WHH);
  bf16_t* bufA = (bf16_t*)(ws + OFF_BUFA);   // X1, then Q2
  bf16_t* bufB = (bf16_t*)(ws + OFF_BUFB);   // H,  then Q3

  float* q_out = (float*)d_out;                       // [NR][64]
  float* h_out = q_out + (size_t)NR * NACT;           // [NR][512]

  k_prep<<<7936, 256, 0, stream>>>(fc1_w, fc1_t, fc2_w, fc2_t, fc3_w, fc3_t,
                                   fc4_w, fc4_t, gru_wih, gru_whh,
                                   wm1, wm2, wm3, wm4, wihb, whhb, meta);
  k_count<<<64, 256, 0, stream>>>(ids, meta);
  k_td<<<1, 64, 0, stream>>>(meta);
  k_scatter<<<64, 256, 0, stream>>>(ids, meta, perm);

  // fc1: gather fp32 inputs, relu -> bufA (sorted bf16)
  k_fc<128, HID, true, 0><<<dim3(MAXTILES, 4), 256, 0, stream>>>(
      inputs, nullptr, wm1, fc1_b, bufA, nullptr, meta, perm);
  // GRU: bufA + gathered hidden -> bufB (bf16) + h_out (fp32, scattered)
  k_gru<<<dim3(NR/BMT, 4), 512, 0, stream>>>(bufA, hidden, wihb, whhb,
                                             gru_bih, gru_bhh, bufB, h_out, perm);
  // fc2: bufB -> bufA
  k_fc<128, HID, false, 0><<<dim3(MAXTILES, 4), 256, 0, stream>>>(
      nullptr, bufB, wm2, fc2_b, bufA, nullptr, meta, perm);
  // fc3: bufA -> bufB
  k_fc<128, HID, false, 0><<<dim3(MAXTILES, 4), 256, 0, stream>>>(
      nullptr, bufA, wm3, fc3_b, bufB, nullptr, meta, perm);
  // fc4: bufB -> q_out (fp32, scattered, no relu)
  k_fc<64, NACT, false, 1><<<dim3(MAXTILES, 1), 256, 0, stream>>>(
      nullptr, bufB, wm4, fc4_b, nullptr, q_out, meta, perm);
}